// Round 5
// baseline (362.699 us; speedup 1.0000x reference)
//
#include <hip/hip_runtime.h>
#include <stdint.h>

typedef __attribute__((ext_vector_type(8))) short short8;
typedef __attribute__((ext_vector_type(4))) float floatx4;

#define B_DIM 8192
#define K_DIM 2048
#define N_DIM 2048
#define PREP_X_BLOCKS 8192   // 8192 blocks * 256 thr * 8 floats = 16.8M elems of X

// round-to-nearest-even fp32 -> bf16
__device__ __forceinline__ unsigned short f2bf(float f) {
    union { float f; unsigned u; } v; v.f = f;
    unsigned r = v.u + 0x7fffu + ((v.u >> 16) & 1u);
    return (unsigned short)(r >> 16);
}
__device__ __forceinline__ unsigned pack2bf(float a, float b) {
    return (unsigned)f2bf(a) | ((unsigned)f2bf(b) << 16);
}
__device__ __forceinline__ float sigm(float x) { return 1.f / (1.f + __expf(-x)); }

__device__ __forceinline__ void gld_lds16(const void* g, void* l) {
    __builtin_amdgcn_global_load_lds(
        (const __attribute__((address_space(1))) void*)g,
        (__attribute__((address_space(3))) void*)l, 16, 0, 0);
}

// ---------------- merged prepass (one dispatch) ----------------
// blocks [0, PREP_X_BLOCKS):      X -> Xb (bf16), Lb = bf16(log(|x|+eps))
// blocks [PREP_X_BLOCKS, +1024):  Wt[n][k] = bf16(tanh(Wh)*sigmoid(Mh)),
//                                 Gt[n][k] = bf16(gate)   (64x64 transpose tiles)
__global__ __launch_bounds__(256) void prep_all(const float4* __restrict__ X4,
                                                ushort* __restrict__ Xb,
                                                ushort* __restrict__ Lb,
                                                const float* __restrict__ Wh,
                                                const float* __restrict__ Mh,
                                                const float* __restrict__ Gf,
                                                ushort* __restrict__ Wt,
                                                ushort* __restrict__ Gt) {
    __shared__ ushort sw[64 * 66];
    __shared__ ushort sg[64 * 66];
    const int t = threadIdx.x;
    int bid = blockIdx.x;
    if (bid < PREP_X_BLOCKS) {
        size_t i = (size_t)bid * 512 + t;
#pragma unroll
        for (int h = 0; h < 2; h++) {
            float4 v = X4[i + h * 256];
            ushort4 xb, lb;
            xb.x = f2bf(v.x); xb.y = f2bf(v.y); xb.z = f2bf(v.z); xb.w = f2bf(v.w);
            lb.x = f2bf(__logf(fabsf(v.x) + 1e-7f));
            lb.y = f2bf(__logf(fabsf(v.y) + 1e-7f));
            lb.z = f2bf(__logf(fabsf(v.z) + 1e-7f));
            lb.w = f2bf(__logf(fabsf(v.w) + 1e-7f));
            *(ushort4*)(Xb + (i + h * 256) * 4) = xb;
            *(ushort4*)(Lb + (i + h * 256) * 4) = lb;
        }
        return;
    }
    bid -= PREP_X_BLOCKS;
    const int n0 = (bid & 31) * 64;
    const int k0 = (bid >> 5) * 64;
    const int kr = t >> 4;          // 0..15
    const int nc = (t & 15) * 4;    // 0..60, float4 column
#pragma unroll
    for (int p = 0; p < 4; p++) {
        const int kl = kr + p * 16;
        const size_t idx = (size_t)(k0 + kl) * N_DIM + n0 + nc;
        float4 wh = *(const float4*)(Wh + idx);
        float4 mh = *(const float4*)(Mh + idx);
        float4 gf = *(const float4*)(Gf + idx);
        const int la = kl * 66 + nc;          // even -> 4B aligned
        *(unsigned*)(sw + la)     = pack2bf(tanhf(wh.x) * sigm(mh.x), tanhf(wh.y) * sigm(mh.y));
        *(unsigned*)(sw + la + 2) = pack2bf(tanhf(wh.z) * sigm(mh.z), tanhf(wh.w) * sigm(mh.w));
        *(unsigned*)(sg + la)     = pack2bf(gf.x, gf.y);
        *(unsigned*)(sg + la + 2) = pack2bf(gf.z, gf.w);
    }
    __syncthreads();
    // transposed write-out: 4 lanes cover one n-row (128B contiguous)
    const int nl = t >> 2;          // 0..63 local n
    const int kg = t & 3;           // 16-k chunk
    ushort tw[16], tg[16];
#pragma unroll
    for (int j = 0; j < 16; j++) {
        const int k = kg * 16 + j;
        tw[j] = sw[k * 66 + nl];
        tg[j] = sg[k * 66 + nl];
    }
    const size_t o = (size_t)(n0 + nl) * K_DIM + k0 + kg * 16;
    short8 vw0 = {(short)tw[0],(short)tw[1],(short)tw[2],(short)tw[3],(short)tw[4],(short)tw[5],(short)tw[6],(short)tw[7]};
    short8 vw1 = {(short)tw[8],(short)tw[9],(short)tw[10],(short)tw[11],(short)tw[12],(short)tw[13],(short)tw[14],(short)tw[15]};
    short8 vg0 = {(short)tg[0],(short)tg[1],(short)tg[2],(short)tg[3],(short)tg[4],(short)tg[5],(short)tg[6],(short)tg[7]};
    short8 vg1 = {(short)tg[8],(short)tg[9],(short)tg[10],(short)tg[11],(short)tg[12],(short)tg[13],(short)tg[14],(short)tg[15]};
    *(short8*)(Wt + o) = vw0;
    *(short8*)(Wt + o + 8) = vw1;
    *(short8*)(Gt + o) = vg0;
    *(short8*)(Gt + o + 8) = vg1;
}

// ---------------- fused GEMM: a = Xb@Wt^T, lm = Lb@Wt^T, gl = Xb@Gt^T ----------------
// out = sigmoid(gl)*a + (1-sigmoid(gl))*exp(lm)
// 128x128 block tile, 4 waves (2x2), BK=32, __launch_bounds__(256,2) -> 2 blocks/CU.
// XOR-swizzled LDS k-chunks: chunk' = chunk ^ ((row>>1)&3). Staging lanes fetch the
// permuted global chunk (same 64B line -> coalescing intact); fragment reads apply
// the same XOR. Kills the structural 8-way bank conflict of the 64B-row-stride
// layout (-> exact 2-way aliasing, free per m136).
__global__ __launch_bounds__(256, 2) void gemm_fused(const ushort* __restrict__ Xb,
                                                     const ushort* __restrict__ Lb,
                                                     const ushort* __restrict__ Wt,
                                                     const ushort* __restrict__ Gt,
                                                     float* __restrict__ out) {
    __shared__ ushort smem[4 * 128 * 32];   // [sX | sL | sW | sG]
    ushort* sX = smem;
    ushort* sL = smem + 1 * 128 * 32;
    ushort* sW = smem + 2 * 128 * 32;
    ushort* sG = smem + 3 * 128 * 32;

    const int t = threadIdx.x;
    const int lane = t & 63;
    const int w = t >> 6;
    const int wm = w >> 1, wn = w & 1;
    const int rowA = blockIdx.y * 128;
    const int rowB = blockIdx.x * 128;

    floatx4 acca[4][4], accm[4][4], accg[4][4];
    const floatx4 z = {0.f, 0.f, 0.f, 0.f};
#pragma unroll
    for (int i = 0; i < 4; i++)
#pragma unroll
        for (int j = 0; j < 4; j++) { acca[i][j] = z; accm[i][j] = z; accg[i][j] = z; }

    const int r0 = t >> 2;                               // staged row 0..63
    const int cs = (((t & 3) ^ ((t >> 3) & 3)) << 3);    // swizzled global k-chunk
    const int aoff0 = (rowA + r0) * K_DIM + cs;
    const int aoff1 = aoff0 + 64 * K_DIM;
    const int boff0 = (rowB + r0) * K_DIM + cs;
    const int boff1 = boff0 + 64 * K_DIM;

    const int lr = lane & 15;
    const int xorc = (((lane >> 4) ^ ((lr >> 1) & 3)) << 3);  // swizzled read chunk
    const ushort* rdA = sX + (wm * 64 + lr) * 32 + xorc;      // +128*32 -> sL section
    const ushort* rdB = sW + (wn * 64 + lr) * 32 + xorc;      // +128*32 -> sG section

    for (int k0 = 0; k0 < K_DIM; k0 += 32) {
        gld_lds16(Xb + aoff0 + k0, sX + t * 8);
        gld_lds16(Xb + aoff1 + k0, sX + (t + 256) * 8);
        gld_lds16(Lb + aoff0 + k0, sL + t * 8);
        gld_lds16(Lb + aoff1 + k0, sL + (t + 256) * 8);
        gld_lds16(Wt + boff0 + k0, sW + t * 8);
        gld_lds16(Wt + boff1 + k0, sW + (t + 256) * 8);
        gld_lds16(Gt + boff0 + k0, sG + t * 8);
        gld_lds16(Gt + boff1 + k0, sG + (t + 256) * 8);
        asm volatile("s_waitcnt vmcnt(0)" ::: "memory");
        __syncthreads();
        short8 bw[4], bg[4];
#pragma unroll
        for (int ni = 0; ni < 4; ni++) {
            bw[ni] = *(const short8*)(rdB + ni * 16 * 32);
            bg[ni] = *(const short8*)(rdB + (128 * 32) + ni * 16 * 32);
        }
#pragma unroll
        for (int mi = 0; mi < 4; mi++) {
            short8 ax = *(const short8*)(rdA + mi * 16 * 32);
            short8 al = *(const short8*)(rdA + (128 * 32) + mi * 16 * 32);
#pragma unroll
            for (int ni = 0; ni < 4; ni++) {
                acca[mi][ni] = __builtin_amdgcn_mfma_f32_16x16x32_bf16(ax, bw[ni], acca[mi][ni], 0, 0, 0);
                accm[mi][ni] = __builtin_amdgcn_mfma_f32_16x16x32_bf16(al, bw[ni], accm[mi][ni], 0, 0, 0);
                accg[mi][ni] = __builtin_amdgcn_mfma_f32_16x16x32_bf16(ax, bg[ni], accg[mi][ni], 0, 0, 0);
            }
        }
        __syncthreads();
    }

    const int rsub = (lane >> 4) << 2;
#pragma unroll
    for (int mi = 0; mi < 4; mi++)
#pragma unroll
        for (int ni = 0; ni < 4; ni++)
#pragma unroll
            for (int r = 0; r < 4; r++) {
                int row = rowA + wm * 64 + mi * 16 + rsub + r;
                int col = rowB + wn * 64 + ni * 16 + lr;
                float g = sigm(accg[mi][ni][r]);
                float a = acca[mi][ni][r];
                float m = __expf(accm[mi][ni][r]);
                out[(size_t)row * N_DIM + col] = g * a + (1.f - g) * m;
            }
}

extern "C" void kernel_launch(void* const* d_in, const int* in_sizes, int n_in,
                              void* d_out, int out_size, void* d_ws, size_t ws_size,
                              hipStream_t stream) {
    const float* X  = (const float*)d_in[0];
    const float* Wh = (const float*)d_in[1];
    const float* Mh = (const float*)d_in[2];
    const float* Gf = (const float*)d_in[3];
    float* out = (float*)d_out;

    // workspace layout (bytes):
    //   Xb : B*K*2  = 33,554,432
    //   Lb : B*K*2  = 33,554,432
    //   Wt : N*K*2  =  8,388,608   (transposed: [n][k])
    //   Gt : N*K*2  =  8,388,608
    char* ws = (char*)d_ws;
    ushort* Xb = (ushort*)(ws);
    ushort* Lb = (ushort*)(ws + (size_t)B_DIM * K_DIM * 2);
    ushort* Wt = (ushort*)(ws + (size_t)B_DIM * K_DIM * 4);
    ushort* Gt = (ushort*)(ws + (size_t)B_DIM * K_DIM * 4 + (size_t)N_DIM * K_DIM * 2);

    // one prep dispatch: X-conversion blocks + weight-transform blocks
    prep_all<<<dim3(PREP_X_BLOCKS + (N_DIM / 64) * (K_DIM / 64)), dim3(256), 0, stream>>>(
        (const float4*)X, Xb, Lb, Wh, Mh, Gf, Wt, Gt);

    gemm_fused<<<dim3(N_DIM / 128, B_DIM / 128), dim3(256), 0, stream>>>(Xb, Lb, Wt, Gt, out);
}